// Round 3
// baseline (62.829 us; speedup 1.0000x reference)
//
#include <hip/hip_runtime.h>

#define EPSV   1e-6f
#define SMOOTH 0.025f
#define HALF   4096      // chunk0 = [0,4096), chunk1 = [4096,T)
#define WARM   512       // EMA warm-up steps for chunk1 (a^512 ~ 2.4e-6)

__device__ __forceinline__ float fast_log2(float v) { return __builtin_amdgcn_logf(v); }
__device__ __forceinline__ float fast_exp2(float v) { return __builtin_amdgcn_exp2f(v); }

// PCEN pointwise: y = (x/(eps+M)^alpha + delta)^r - delta^r
__device__ __forceinline__ float pcen_elem(float xr, float M, float nalpha,
                                           float delta, float r, float dr) {
    float m    = EPSV + M;
    float norm = xr * fast_exp2(nalpha * fast_log2(m));   // x * m^-alpha
    return fast_exp2(r * fast_log2(norm + delta)) - dr;
}

struct C8 {
    float a1,a2,a3,a4,a5,a6,a7,a8;     // a^k
    float d0,d1,d2,d3,d4,d5;           // a^(8*2^s)
    float a8lane;                      // a^(8*lane)
    float b;
    int   lane;
};

// Wave-parallel scan of M_t = a*M_{t-1} + b*x_t over a 512-elem tile
// (8 contiguous elems per lane). Returns carry (M at last element).
__device__ __forceinline__ float scan8(const C8& c, const float xr[8],
                                       float m0, float M[8]) {
    float q0 = c.b * xr[0];
    float q1 = fmaf(c.a1, q0, c.b * xr[1]);
    float q2 = fmaf(c.a1, q1, c.b * xr[2]);
    float q3 = fmaf(c.a1, q2, c.b * xr[3]);
    float q4 = fmaf(c.a1, q3, c.b * xr[4]);
    float q5 = fmaf(c.a1, q4, c.b * xr[5]);
    float q6 = fmaf(c.a1, q5, c.b * xr[6]);
    float q7 = fmaf(c.a1, q6, c.b * xr[7]);

    float P = q7, up;
    up = __shfl_up(P, 1, 64);  P = fmaf(c.lane >= 1  ? c.d0 : 0.0f, up, P);
    up = __shfl_up(P, 2, 64);  P = fmaf(c.lane >= 2  ? c.d1 : 0.0f, up, P);
    up = __shfl_up(P, 4, 64);  P = fmaf(c.lane >= 4  ? c.d2 : 0.0f, up, P);
    up = __shfl_up(P, 8, 64);  P = fmaf(c.lane >= 8  ? c.d3 : 0.0f, up, P);
    up = __shfl_up(P, 16, 64); P = fmaf(c.lane >= 16 ? c.d4 : 0.0f, up, P);
    up = __shfl_up(P, 32, 64); P = fmaf(c.lane >= 32 ? c.d5 : 0.0f, up, P);
    float Pexc = __shfl_up(P, 1, 64);
    if (c.lane == 0) Pexc = 0.0f;

    float state = fmaf(c.a8lane, m0, Pexc);  // M entering this lane's block
    M[0] = fmaf(c.a1, state, q0);
    M[1] = fmaf(c.a2, state, q1);
    M[2] = fmaf(c.a3, state, q2);
    M[3] = fmaf(c.a4, state, q3);
    M[4] = fmaf(c.a5, state, q4);
    M[5] = fmaf(c.a6, state, q5);
    M[6] = fmaf(c.a7, state, q6);
    M[7] = fmaf(c.a8, state, q7);
    return __shfl(M[7], 63, 64);
}

__global__ __launch_bounds__(256, 8) void pcen_ema_kernel(
    const float* __restrict__ x,
    const float* __restrict__ alpha_p,
    const float* __restrict__ delta_p,
    const float* __restrict__ r_p,
    float* __restrict__ y,
    int rows, int T)
{
    const int gid   = blockIdx.x * blockDim.x + threadIdx.x;
    const int wave  = gid >> 6;
    const int lane  = gid & 63;
    const int row   = wave >> 1;
    const int chunk = wave & 1;
    if (row >= rows) return;

    const float nalpha = -alpha_p[0];
    const float delta  = delta_p[0];
    const float r      = r_p[0];
    const float dr     = fast_exp2(r * fast_log2(delta));

    C8 c;
    c.lane = lane;
    c.b  = SMOOTH;
    const float a = 1.0f - SMOOTH;
    c.a1 = a;        c.a2 = a*a;      c.a3 = c.a2*a;   c.a4 = c.a2*c.a2;
    c.a5 = c.a4*a;   c.a6 = c.a4*c.a2; c.a7 = c.a4*c.a3; c.a8 = c.a4*c.a4;
    c.d0 = c.a8;       c.d1 = c.d0*c.d0; c.d2 = c.d1*c.d1;
    c.d3 = c.d2*c.d2;  c.d4 = c.d3*c.d3; c.d5 = c.d4*c.d4;
    float a8l = 1.0f;
    if (lane & 1)  a8l *= c.d0;
    if (lane & 2)  a8l *= c.d1;
    if (lane & 4)  a8l *= c.d2;
    if (lane & 8)  a8l *= c.d3;
    if (lane & 16) a8l *= c.d4;
    if (lane & 32) a8l *= c.d5;
    c.a8lane = a8l;

    const long long base = (long long)row * T;
    const float* __restrict__ xrow = x + base;
    float* __restrict__       yrow = y + base;

    const int tstart = chunk ? HALF : 0;
    const int tend   = chunk ? T    : HALF;

    float m0 = 0.0f;

    // chunk1: 512-step EMA warm-up (no stores) starting from M=0
    if (chunk) {
        const int tw = HALF - WARM;
        float4 w0 = *(const float4*)(xrow + tw + 8 * lane);
        float4 w1 = *(const float4*)(xrow + tw + 8 * lane + 4);
        float xr[8] = { fmaxf(w0.x,0.f), fmaxf(w0.y,0.f), fmaxf(w0.z,0.f), fmaxf(w0.w,0.f),
                        fmaxf(w1.x,0.f), fmaxf(w1.y,0.f), fmaxf(w1.z,0.f), fmaxf(w1.w,0.f) };
        float Mt[8];
        m0 = scan8(c, xr, 0.0f, Mt);
    }

    const int nfull = (tend - tstart) >> 9;   // full 512-elem tiles
    int t = tstart;

    float4 v0 = make_float4(0,0,0,0), v1 = v0;
    if (nfull > 0) {
        v0 = *(const float4*)(xrow + t + 8 * lane);
        v1 = *(const float4*)(xrow + t + 8 * lane + 4);
    }
    for (int i = 0; i < nfull; ++i) {
        // prefetch next tile before touching the carry-serialized scan
        float4 n0 = make_float4(0,0,0,0), n1 = n0;
        const int tn = t + 512;
        if (i + 1 < nfull) {
            n0 = *(const float4*)(xrow + tn + 8 * lane);
            n1 = *(const float4*)(xrow + tn + 8 * lane + 4);
        }

        float xr[8] = { fmaxf(v0.x,0.f), fmaxf(v0.y,0.f), fmaxf(v0.z,0.f), fmaxf(v0.w,0.f),
                        fmaxf(v1.x,0.f), fmaxf(v1.y,0.f), fmaxf(v1.z,0.f), fmaxf(v1.w,0.f) };
        float M[8];
        m0 = scan8(c, xr, m0, M);

        float4 o0, o1;
        o0.x = pcen_elem(xr[0], M[0], nalpha, delta, r, dr);
        o0.y = pcen_elem(xr[1], M[1], nalpha, delta, r, dr);
        o0.z = pcen_elem(xr[2], M[2], nalpha, delta, r, dr);
        o0.w = pcen_elem(xr[3], M[3], nalpha, delta, r, dr);
        o1.x = pcen_elem(xr[4], M[4], nalpha, delta, r, dr);
        o1.y = pcen_elem(xr[5], M[5], nalpha, delta, r, dr);
        o1.z = pcen_elem(xr[6], M[6], nalpha, delta, r, dr);
        o1.w = pcen_elem(xr[7], M[7], nalpha, delta, r, dr);
        *(float4*)(yrow + t + 8 * lane)     = o0;
        *(float4*)(yrow + t + 8 * lane + 4) = o1;

        v0 = n0; v1 = n1; t = tn;
    }

    // masked tail (< 512 elems), scalar per-element with bounds checks
    if (t < tend) {
        const int b8 = t + 8 * lane;
        float xr[8];
        #pragma unroll
        for (int k = 0; k < 8; ++k) {
            int idx = b8 + k;
            xr[k] = (idx < tend) ? fmaxf(xrow[idx], 0.0f) : 0.0f;
        }
        float M[8];
        scan8(c, xr, m0, M);
        #pragma unroll
        for (int k = 0; k < 8; ++k) {
            int idx = b8 + k;
            if (idx < tend) yrow[idx] = pcen_elem(xr[k], M[k], nalpha, delta, r, dr);
        }
    }
}

extern "C" void kernel_launch(void* const* d_in, const int* in_sizes, int n_in,
                              void* d_out, int out_size, void* d_ws, size_t ws_size,
                              hipStream_t stream) {
    const float* x     = (const float*)d_in[0];
    const float* alpha = (const float*)d_in[1];
    const float* delta = (const float*)d_in[2];
    const float* r     = (const float*)d_in[3];
    float* y = (float*)d_out;

    const int T     = 8000;
    const int total = in_sizes[0];
    const int rows  = total / T;              // 4096

    const int waves   = rows * 2;             // 2 T-chunks per row
    const int threads = waves * 64;
    const int block   = 256;
    const int grid    = (threads + block - 1) / block;
    pcen_ema_kernel<<<grid, block, 0, stream>>>(x, alpha, delta, r, y, rows, T);
}

// Round 4
// 46.915 us; speedup vs baseline: 1.3392x; 1.3392x over previous
//
#include <hip/hip_runtime.h>

#define EPSV   1e-6f
#define SMOOTH 0.025f
#define HALF   4096      // chunk0 = [0,4096), chunk1 = [4096,T)
#define WARM   512       // EMA warm-up steps for chunk1 (a^512 ~ 2.4e-6)

typedef float v4f __attribute__((ext_vector_type(4)));

__device__ __forceinline__ float fast_log2(float v) { return __builtin_amdgcn_logf(v); }
__device__ __forceinline__ float fast_exp2(float v) { return __builtin_amdgcn_exp2f(v); }

// PCEN pointwise: y = (x/(eps+M)^alpha + delta)^r - delta^r
__device__ __forceinline__ float pcen_elem(float xr, float M, float nalpha,
                                           float delta, float r, float dr) {
    float m    = EPSV + M;
    float norm = xr * fast_exp2(nalpha * fast_log2(m));   // x * m^-alpha
    return fast_exp2(r * fast_log2(norm + delta)) - dr;
}

struct KC {
    float a1, a2, a3, a4;            // a^k
    float e0, e1, e2, e3, e4, e5;    // a^(4*2^s)
    float a4lane;                    // a^(4*lane)
    float a256;                      // a^256
    int   lane;
};

// Scan of M_t = a*M_{t-1} + b*x_t over a 512-elem group laid out as two
// coalesced 256-elem tiles (lane owns A[4l..4l+3], B[256+4l..]). The two
// Kogge-Stone chains are independent and interleave; the carry enters only
// via 2 trailing FMAs, keeping the cross-group critical path tiny.
__device__ __forceinline__ void scan_group(const KC& c,
                                           const float xa[4], const float xb[4],
                                           float& m0, float Ma[4], float Mb[4]) {
    const float b = SMOOTH;
    float qa0 = b * xa[0];
    float qa1 = fmaf(c.a1, qa0, b * xa[1]);
    float qa2 = fmaf(c.a1, qa1, b * xa[2]);
    float qa3 = fmaf(c.a1, qa2, b * xa[3]);
    float qb0 = b * xb[0];
    float qb1 = fmaf(c.a1, qb0, b * xb[1]);
    float qb2 = fmaf(c.a1, qb1, b * xb[2]);
    float qb3 = fmaf(c.a1, qb2, b * xb[3]);

    float PA = qa3, PB = qb3, u;
    u = __shfl_up(PA, 1, 64);  PA = fmaf(c.lane >= 1  ? c.e0 : 0.f, u, PA);
    u = __shfl_up(PB, 1, 64);  PB = fmaf(c.lane >= 1  ? c.e0 : 0.f, u, PB);
    u = __shfl_up(PA, 2, 64);  PA = fmaf(c.lane >= 2  ? c.e1 : 0.f, u, PA);
    u = __shfl_up(PB, 2, 64);  PB = fmaf(c.lane >= 2  ? c.e1 : 0.f, u, PB);
    u = __shfl_up(PA, 4, 64);  PA = fmaf(c.lane >= 4  ? c.e2 : 0.f, u, PA);
    u = __shfl_up(PB, 4, 64);  PB = fmaf(c.lane >= 4  ? c.e2 : 0.f, u, PB);
    u = __shfl_up(PA, 8, 64);  PA = fmaf(c.lane >= 8  ? c.e3 : 0.f, u, PA);
    u = __shfl_up(PB, 8, 64);  PB = fmaf(c.lane >= 8  ? c.e3 : 0.f, u, PB);
    u = __shfl_up(PA, 16, 64); PA = fmaf(c.lane >= 16 ? c.e4 : 0.f, u, PA);
    u = __shfl_up(PB, 16, 64); PB = fmaf(c.lane >= 16 ? c.e4 : 0.f, u, PB);
    u = __shfl_up(PA, 32, 64); PA = fmaf(c.lane >= 32 ? c.e5 : 0.f, u, PA);
    u = __shfl_up(PB, 32, 64); PB = fmaf(c.lane >= 32 ? c.e5 : 0.f, u, PB);

    float TA = __shfl(PA, 63, 64);              // tile totals
    float TB = __shfl(PB, 63, 64);
    float PexcA = __shfl_up(PA, 1, 64); if (c.lane == 0) PexcA = 0.f;
    float PexcB = __shfl_up(PB, 1, 64); if (c.lane == 0) PexcB = 0.f;

    float mA = m0;                              // state entering tile A
    float mB = fmaf(c.a256, m0, TA);            // entering tile B
    m0       = fmaf(c.a256, mB, TB);            // carry out (2-FMA chain)

    float sA = fmaf(c.a4lane, mA, PexcA);
    float sB = fmaf(c.a4lane, mB, PexcB);
    Ma[0] = fmaf(c.a1, sA, qa0);
    Ma[1] = fmaf(c.a2, sA, qa1);
    Ma[2] = fmaf(c.a3, sA, qa2);
    Ma[3] = fmaf(c.a4, sA, qa3);
    Mb[0] = fmaf(c.a1, sB, qb0);
    Mb[1] = fmaf(c.a2, sB, qb1);
    Mb[2] = fmaf(c.a3, sB, qb2);
    Mb[3] = fmaf(c.a4, sB, qb3);
}

__global__ __launch_bounds__(256, 6) void pcen_ema_kernel(
    const float* __restrict__ x,
    const float* __restrict__ alpha_p,
    const float* __restrict__ delta_p,
    const float* __restrict__ r_p,
    float* __restrict__ y,
    int rows, int T)
{
    const int gid   = blockIdx.x * blockDim.x + threadIdx.x;
    const int wave  = gid >> 6;
    const int lane  = gid & 63;
    const int row   = wave >> 1;
    const int chunk = wave & 1;
    if (row >= rows) return;

    const float nalpha = -alpha_p[0];
    const float delta  = delta_p[0];
    const float r      = r_p[0];
    const float dr     = fast_exp2(r * fast_log2(delta));

    KC c;
    c.lane = lane;
    const float a = 1.0f - SMOOTH;
    c.a1 = a;  c.a2 = a * a;  c.a3 = c.a2 * a;  c.a4 = c.a2 * c.a2;
    c.e0 = c.a4;      c.e1 = c.e0 * c.e0;  c.e2 = c.e1 * c.e1;
    c.e3 = c.e2 * c.e2; c.e4 = c.e3 * c.e3; c.e5 = c.e4 * c.e4;
    c.a256 = c.e5 * c.e5;
    float a4l = 1.0f;
    if (lane & 1)  a4l *= c.e0;
    if (lane & 2)  a4l *= c.e1;
    if (lane & 4)  a4l *= c.e2;
    if (lane & 8)  a4l *= c.e3;
    if (lane & 16) a4l *= c.e4;
    if (lane & 32) a4l *= c.e5;
    c.a4lane = a4l;

    const long long base = (long long)row * T;
    const float* __restrict__ xrow = x + base;
    float* __restrict__       yrow = y + base;

    const int tstart = chunk ? HALF : 0;
    const int tend   = chunk ? T    : HALF;
    const int off    = 4 * lane;

    float m0 = 0.0f;

    // chunk1: 512-step warm-up (no stores), coalesced 2-tile group
    if (chunk) {
        const int tw = HALF - WARM;
        v4f wa = *(const v4f*)(xrow + tw + off);
        v4f wb = *(const v4f*)(xrow + tw + 256 + off);
        float xa[4] = { fmaxf(wa.x,0.f), fmaxf(wa.y,0.f), fmaxf(wa.z,0.f), fmaxf(wa.w,0.f) };
        float xb[4] = { fmaxf(wb.x,0.f), fmaxf(wb.y,0.f), fmaxf(wb.z,0.f), fmaxf(wb.w,0.f) };
        float Ma[4], Mb[4];
        scan_group(c, xa, xb, m0, Ma, Mb);
    }

    const int nfull = (tend - tstart) >> 9;   // full 512-elem groups
    int t = tstart;

    v4f va = {0,0,0,0}, vb = va;
    if (nfull > 0) {
        va = *(const v4f*)(xrow + t + off);
        vb = *(const v4f*)(xrow + t + 256 + off);
    }
    for (int i = 0; i < nfull; ++i) {
        // prefetch next group (clamped to a valid in-row address; wave-uniform)
        const int tn = t + 512;
        const int tp = (i + 1 < nfull) ? tn : t;
        v4f na = *(const v4f*)(xrow + tp + off);
        v4f nb = *(const v4f*)(xrow + tp + 256 + off);

        float xa[4] = { fmaxf(va.x,0.f), fmaxf(va.y,0.f), fmaxf(va.z,0.f), fmaxf(va.w,0.f) };
        float xb[4] = { fmaxf(vb.x,0.f), fmaxf(vb.y,0.f), fmaxf(vb.z,0.f), fmaxf(vb.w,0.f) };
        float Ma[4], Mb[4];
        scan_group(c, xa, xb, m0, Ma, Mb);

        v4f oa, ob;
        oa.x = pcen_elem(xa[0], Ma[0], nalpha, delta, r, dr);
        oa.y = pcen_elem(xa[1], Ma[1], nalpha, delta, r, dr);
        oa.z = pcen_elem(xa[2], Ma[2], nalpha, delta, r, dr);
        oa.w = pcen_elem(xa[3], Ma[3], nalpha, delta, r, dr);
        ob.x = pcen_elem(xb[0], Mb[0], nalpha, delta, r, dr);
        ob.y = pcen_elem(xb[1], Mb[1], nalpha, delta, r, dr);
        ob.z = pcen_elem(xb[2], Mb[2], nalpha, delta, r, dr);
        ob.w = pcen_elem(xb[3], Mb[3], nalpha, delta, r, dr);
        // nt stores: y is never re-read; keep x resident in L3
        __builtin_nontemporal_store(oa, (v4f*)(yrow + t + off));
        __builtin_nontemporal_store(ob, (v4f*)(yrow + t + 256 + off));

        va = na; vb = nb; t = tn;
    }

    // masked tail group (< 512 elems), per-element predication
    if (t < tend) {
        float xa[4], xb[4];
        #pragma unroll
        for (int k = 0; k < 4; ++k) {
            int ia = t + off + k;
            int ib = t + 256 + off + k;
            xa[k] = (ia < tend) ? fmaxf(xrow[ia], 0.f) : 0.f;
            xb[k] = (ib < tend) ? fmaxf(xrow[ib], 0.f) : 0.f;
        }
        float Ma[4], Mb[4];
        scan_group(c, xa, xb, m0, Ma, Mb);
        #pragma unroll
        for (int k = 0; k < 4; ++k) {
            int ia = t + off + k;
            int ib = t + 256 + off + k;
            if (ia < tend) yrow[ia] = pcen_elem(xa[k], Ma[k], nalpha, delta, r, dr);
            if (ib < tend) yrow[ib] = pcen_elem(xb[k], Mb[k], nalpha, delta, r, dr);
        }
    }
}

extern "C" void kernel_launch(void* const* d_in, const int* in_sizes, int n_in,
                              void* d_out, int out_size, void* d_ws, size_t ws_size,
                              hipStream_t stream) {
    const float* x     = (const float*)d_in[0];
    const float* alpha = (const float*)d_in[1];
    const float* delta = (const float*)d_in[2];
    const float* r     = (const float*)d_in[3];
    float* y = (float*)d_out;

    const int T     = 8000;
    const int total = in_sizes[0];
    const int rows  = total / T;              // 4096

    const int waves   = rows * 2;             // 2 T-chunks per row
    const int threads = waves * 64;
    const int block   = 256;
    const int grid    = (threads + block - 1) / block;
    pcen_ema_kernel<<<grid, block, 0, stream>>>(x, alpha, delta, r, y, rows, T);
}